// Round 13
// baseline (193.077 us; speedup 1.0000x reference)
//
#include <hip/hip_runtime.h>
#include <hip/hip_bf16.h>

// B=16384 W=5 L=20 E=50 V=100000 C=128 H=4096 O=50
// wbf  = bf16 fc1 weights in MFMA A-frag layout:                 ws+8M    (2 MB)
// w2bf = bf16 fc2 weights in MFMA B-frag layout:                 ws+10M   (0.5 MB)
// gt4  = conv table fp16 [128][50][4] = {kk0,kk1,kk2,pad}        ws+11M   (50 KB)
// R12 post-mortem: 16B taps + wer prefetch = null (fused 112->114). The ~30us
// prologue is LDS-port-BYTE-bound: 20 taps x 800B = 16KB/word -> 6400 b128 x
// ~12cyc = 77k cyc/CU ~ 32us, invariant to instruction slicing (explains
// v2/v3/b128 all null).
// R13: fp16 table -> 8B taps (ds_read_b64, ~6cyc, stride-8 conflict-free):
// halves conv LDS bytes. Precision: table entries ~0.06, fp16 err ~5e-5 on
// the sum; ha's bf16 rounding (~1e-3) dominates 20x -> absmax unchanged.
// 3 cvt_f32_f16/tap (+~4us VALU) vs ~15us LDS saved. FP add order kept.
// Main loop / epilogue byte-identical to R12 (passed).

typedef __attribute__((ext_vector_type(8))) short short8;
typedef __attribute__((ext_vector_type(4))) float float4v;
typedef __attribute__((ext_vector_type(4))) _Float16 half4v;

__device__ inline short bf16b(float f) {
    __hip_bfloat16 h = __float2bfloat16(f);
    return *reinterpret_cast<short*>(&h);
}
__device__ inline uint packbf2(float a, float b) {
    return (uint)(ushort)bf16b(a) | ((uint)(ushort)bf16b(b) << 16);
}
__device__ inline void gload_lds16(const void* g, void* l) {
    __builtin_amdgcn_global_load_lds(
        (const __attribute__((address_space(1))) unsigned int*)g,
        (__attribute__((address_space(3))) unsigned int*)l, 16, 0, 0);
}

// ---------------------------------------------------------------------------
// Merged prep: wbf (blocks 0..4095), w2bf (..5119), gt4 fp16 (..5194)
// ---------------------------------------------------------------------------
__global__ __launch_bounds__(256) void prep_kernel(
    const float* __restrict__ fc1_w, const float* __restrict__ fc1_b,
    const float* __restrict__ fc2_w, const float* __restrict__ char_emb,
    const float* __restrict__ conv_w, short* __restrict__ wbf,
    short* __restrict__ w2bf, _Float16* __restrict__ gt4)
{
    const int bid = blockIdx.x;
    if (bid < 4096) {                       // fc1 weights+bias -> frag order
        int idx = bid * 256 + threadIdx.x;  // n*256 + k
        int n = idx >> 8, k = idx & 255;
        float v = (k < 250) ? fc1_w[n * 250 + k] : (k == 250 ? fc1_b[n] : 0.f);
        int CT = n >> 4, mm = n & 15;
        int ks = k >> 5, qq = (k >> 3) & 3, j = k & 7;
        wbf[((CT * 8 + ks) * 64 + qq * 16 + mm) * 8 + j] = bf16b(v);
    } else if (bid < 5120) {                // fc2 weights (pad 64) -> frag order
        int idx = (bid - 4096) * 256 + threadIdx.x;   // o*4096 + k
        int o = idx >> 12, k = idx & 4095;
        float v = (o < 50) ? fc2_w[idx] : 0.f;
        int Ot = o >> 4, mm = o & 15;
        int kst = k >> 5, qq = (k >> 3) & 3, j = k & 7;
        w2bf[((kst * 4 + Ot) * 64 + qq * 16 + mm) * 8 + j] = bf16b(v);
    } else {                                // conv table -> fp16 [c][o][4] 8B slots
        int idx = (bid - 5120) * 256 + threadIdx.x;   // < 19200
        if (idx >= 19200) return;
        int c = idx / 150, rem = idx - c * 150;
        int kk = rem / 50, o = rem - kk * 50;
        const float* ce = char_emb + c * 50;
        const float* w  = conv_w + o * 150 + kk;
        float s = 0.f;
        #pragma unroll 10
        for (int i = 0; i < 50; ++i) s += ce[i] * w[i * 3];
        gt4[(c * 50 + o) * 4 + kk] = (_Float16)s;
        if (kk == 2) gt4[(c * 50 + o) * 4 + 3] = (_Float16)0.f;   // pad
    }
}

// ---------------------------------------------------------------------------
// Fused conv + fc1 + tanh + fc2 + softmax. 256 blocks x 512 thr, 64 rows.
// LDS map (147456 B total):
//   prologue: gt4 table [0,51200) | cpackS [51200,57600) | xsS [..58880)
//             haS (64x256 bf16, XOR-swz) [110080,142848)
//   main:     Bs dbuf [0,131072) | hsb [131072,147456)
//   epilogue: partf[4][64][64] fp32 [0,65536)
// Waves 2x4: wr = wv>>2 (row half), wc = wv&3 (col quarter = fc2 k-frag).
// Wave-private hs handoff -> one __syncthreads per chunk (R8-proven).
// ---------------------------------------------------------------------------
__global__ __launch_bounds__(512, 1) void fused_kernel(
    const int* __restrict__ x, const int* __restrict__ wci,
    const float* __restrict__ word_emb, const float* __restrict__ conv_b,
    const _Float16* __restrict__ gt4, const short* __restrict__ wbf,
    const short* __restrict__ w2bf, const float* __restrict__ fc2_b,
    float* __restrict__ out)
{
    __shared__ char smem[147456];
    short8* Bsv   = (short8*)smem;               // main loop: [2][4096] frags
    char*   hsb   = smem + 131072;               // 16 KB
    float*  partf = (float*)smem;                // epilogue alias
    char*   gsb   = smem;                        // prologue: conv table (50 KB)
    uint*   cpackS = (uint*)(smem + 51200);      // 320 x 5
    int*    xsS    = (int*)(smem + 57600);       // 320
    char*   haS    = smem + 110080;              // 64 rows x 512 B, swizzled

    const int tid  = threadIdx.x;
    const int lane = tid & 63;
    const int wv   = tid >> 6;
    const int wr = wv >> 2, wc = wv & 3;
    const int q = lane >> 4, m = lane & 15;
    const int m0 = blockIdx.x * 64;
    const int q2base = q >> 1, slot = q & 1;

    const short8* wbfv  = (const short8*)wbf;
    const short8* w2bfv = (const short8*)w2bf;

    // ================= PROLOGUE: conv for this block's 320 words ==========
    {   // stage fp16 table (51200 B) as float4
        const float4* g4 = (const float4*)gt4;
        float4* s4 = (float4*)gsb;
        #pragma unroll
        for (int i = 0; i < 7; ++i) {
            int idx = i * 512 + tid;
            if (idx < 3200) s4[idx] = g4[idx];
        }
    }
    if (tid < 320) {                             // char ids + xid
        const int xid = x[m0 * 5 + tid];
        xsS[tid] = xid;
        const int* crow = wci + (size_t)xid * 20;
        int cid[20];
        #pragma unroll
        for (int p = 0; p < 20; ++p) cid[p] = crow[p];
        #pragma unroll
        for (int u = 0; u < 5; ++u)
            cpackS[tid * 5 + u] = (uint)cid[u * 4] | ((uint)cid[u * 4 + 1] << 8)
                                | ((uint)cid[u * 4 + 2] << 16) | ((uint)cid[u * 4 + 3] << 24);
    }
    // K-bias cols 250..255 (independent of conv; hoisted off critical path)
    if (tid < 384) {
        const int s = tid / 6, j = tid - s * 6;
        const int byteoff = (s * 512 + (250 + j) * 2) ^ ((s & 7) << 4);
        *(short*)(haS + byteoff) = bf16b(j == 0 ? 1.f : 0.f);
    }
    __syncthreads();

    {   // conv: wave wv handles words (g*8+j)*8+wv; lane = out channel
        const int oc = (lane < 50) ? lane : 49;
        const float cbias = conv_b[oc];
        const int oc8 = oc * 8;
        for (int g = 0; g < 5; ++g) {
            float werv[8];                       // 8 gathers in flight (MLP)
            #pragma unroll
            for (int j = 0; j < 8; ++j) {
                const int w = (g * 8 + j) * 8 + wv;
                werv[j] = word_emb[(size_t)xsS[w] * 50 + oc];
            }
            #pragma unroll
            for (int j = 0; j < 8; ++j) {
                const int w = (g * 8 + j) * 8 + wv;
                uint cw[5];
                #pragma unroll
                for (int u = 0; u < 5; ++u) cw[u] = cpackS[w * 5 + u];
                int cb[20];
                #pragma unroll
                for (int p = 0; p < 20; ++p) {
                    const int c = (int)((cw[p >> 2] >> ((p & 3) * 8)) & 0xFF);
                    cb[p] = c * 400 + oc8;       // byte offset of 8B slot
                }
                // phase 1: positions 0..10 (one b64 per tap)
                half4v r[11];
                #pragma unroll
                for (int l = 0; l < 11; ++l) r[l] = *(const half4v*)(gsb + cb[l]);
                float mx = (float)r[0].y + (float)r[1].z;   // (y+ x)+z order kept
                #pragma unroll
                for (int l = 1; l < 10; ++l) {
                    float s = (float)r[l].y + (float)r[l - 1].x + (float)r[l + 1].z;
                    mx = fmaxf(mx, s);
                }
                const half4v r9 = r[9], r10 = r[10];
                // phase 2: positions 11..19
                half4v qv[9];
                #pragma unroll
                for (int l = 0; l < 9; ++l) qv[l] = *(const half4v*)(gsb + cb[11 + l]);
                { float s = (float)r10.y + (float)r9.x + (float)qv[0].z;
                  mx = fmaxf(mx, s); }                                   // l=10
                { float s = (float)qv[0].y + (float)r10.x + (float)qv[1].z;
                  mx = fmaxf(mx, s); }                                   // l=11
                #pragma unroll
                for (int l = 12; l < 19; ++l) {
                    float s = (float)qv[l - 11].y + (float)qv[l - 12].x
                            + (float)qv[l - 10].z;
                    mx = fmaxf(mx, s);
                }
                { float s = (float)qv[8].y + (float)qv[7].x;
                  mx = fmaxf(mx, s); }                                   // l=19

                if (lane < 50) {
                    const int s = w / 5, wp = w - s * 5;
                    const int byteoff = (s * 512 + (wp * 50 + oc) * 2) ^ ((s & 7) << 4);
                    *(short*)(haS + byteoff) = bf16b(mx + cbias + werv[j]);
                }
            }
        }
    }
    __syncthreads();                             // conv done; table dead

    // issue B(0) staging now (overlaps av loads; table region is dead)
    #pragma unroll
    for (int i = 0; i < 8; ++i)
        gload_lds16(wbfv + i * 512 + tid, Bsv + i * 512 + tid);

    // ---- A-frags from haS (swizzled b128 reads): 16 frags = 64 VGPR ----
    short8 av[2][8];
    #pragma unroll
    for (int mt = 0; mt < 2; ++mt)
        #pragma unroll
        for (int ks = 0; ks < 8; ++ks) {
            const int r = wr * 32 + mt * 16 + m;
            const int byteoff = (r * 512 + ks * 64 + q * 16) ^ ((r & 7) << 4);
            av[mt][ks] = *(const short8*)(haS + byteoff);
        }
    #pragma unroll
    for (int mt = 0; mt < 2; ++mt)
        #pragma unroll
        for (int ks = 0; ks < 8; ++ks)
            asm volatile("" : "+v"(av[mt][ks]));
    __syncthreads();                             // drains vmcnt: B(0) ready

    // ================= MAIN LOOP (R8 body, full K: 32 chunks) =============
    float4v acc2[2][4] = {};    // fc2 partial: [row-tile mt][out-tile], k = wc

    #pragma unroll 4
    for (int chg = 0; chg < 32; ++chg) {
        const int buf = chg & 1;

        short8 b2[4];
        #pragma unroll
        for (int Ot = 0; Ot < 4; ++Ot)
            b2[Ot] = w2bfv[(size_t)((chg * 4 + wc) * 4 + Ot) * 64 + lane];

        // async prefetch (chg=31 overruns into w2bf: in-bounds, drained,
        // then overwritten by the partf spill before any read)
        #pragma unroll
        for (int i = 0; i < 8; ++i)
            gload_lds16(wbfv + (size_t)(chg + 1) * 4096 + i * 512 + tid,
                        Bsv + (buf ^ 1) * 4096 + i * 512 + tid);

        // ---- fc1: rows [wr*32,+32) x cols [chg*128 + wc*32, +32) ----
        float4v acc[2][2] = {};
        #pragma unroll
        for (int ks = 0; ks < 8; ++ks) {
            short8 bv[2];
            #pragma unroll
            for (int nt = 0; nt < 2; ++nt)
                bv[nt] = Bsv[buf * 4096 + ((wc * 2 + nt) * 8 + ks) * 64 + lane];
            #pragma unroll
            for (int mt = 0; mt < 2; ++mt)
                #pragma unroll
                for (int nt = 0; nt < 2; ++nt)
                    acc[mt][nt] = __builtin_amdgcn_mfma_f32_16x16x32_bf16(
                        bv[nt], av[mt][ks], acc[mt][nt], 0, 0, 0);
        }

        // ---- tanh + pack to own hs frags (rt = wr*2+mt, kf = wc) ----
        #pragma unroll
        for (int mt = 0; mt < 2; ++mt) {
            const int frag = (wr * 2 + mt) * 4 + wc;
            #pragma unroll
            for (int nt = 0; nt < 2; ++nt) {
                float tv[4];
                #pragma unroll
                for (int r = 0; r < 4; ++r)
                    tv[r] = 1.f - 2.f / (__expf(2.f * acc[mt][nt][r]) + 1.f);
                const int q2 = nt * 2 + q2base;
                const uint p0 = packbf2(tv[0], tv[1]);
                const uint p1 = packbf2(tv[2], tv[3]);
                *(uint2*)(hsb + ((frag * 64 + q2 * 16 + m) * 16 + slot * 8))
                    = make_uint2(p0, p1);
            }
        }

        // ---- fc2 partial: read back OWN frags (same-wave order, no bar) ----
        {
            short8 a2[2];
            #pragma unroll
            for (int mt = 0; mt < 2; ++mt)
                a2[mt] = *(const short8*)(hsb
                    + (((wr * 2 + mt) * 4 + wc) * 64 + lane) * 16);
            #pragma unroll
            for (int mt = 0; mt < 2; ++mt)
                #pragma unroll
                for (int Ot = 0; Ot < 4; ++Ot)
                    acc2[mt][Ot] = __builtin_amdgcn_mfma_f32_16x16x32_bf16(
                        a2[mt], b2[Ot], acc2[mt][Ot], 0, 0, 0);
        }

        __syncthreads();    // Bs[buf] reads done + prefetch vmcnt drained
    }

    // ================= EPILOGUE: reduce + bias + softmax ==================
    #pragma unroll
    for (int mt = 0; mt < 2; ++mt)
        #pragma unroll
        for (int Ot = 0; Ot < 4; ++Ot)
            #pragma unroll
            for (int r = 0; r < 4; ++r)
                partf[(size_t)wc * 4096
                      + ((wr * 2 + mt) * 16 + q * 4 + r) * 64 + Ot * 16 + m]
                    = acc2[mt][Ot][r];
    __syncthreads();

    #pragma unroll
    for (int t = 0; t < 8; ++t) {
        int idx = t * 512 + tid;           // row*64 + col
        int col = idx & 63;
        float lg = partf[idx] + partf[4096 + idx]
                 + partf[8192 + idx] + partf[12288 + idx];
        partf[idx] = (col < 50) ? lg + fc2_b[col] : -1e30f;
    }
    __syncthreads();

    #pragma unroll
    for (int rr = 0; rr < 8; ++rr) {
        const int row = wv * 8 + rr;
        float v = partf[row * 64 + lane];
        float mx = v;
        #pragma unroll
        for (int off = 32; off > 0; off >>= 1) mx = fmaxf(mx, __shfl_xor(mx, off));
        float e = __expf(v - mx);
        float s = e;
        #pragma unroll
        for (int off = 32; off > 0; off >>= 1) s += __shfl_xor(s, off);
        if (lane < 50)
            out[(size_t)(m0 + row) * 50 + lane] = e / s;
    }
}

// ---------------------------------------------------------------------------
extern "C" void kernel_launch(void* const* d_in, const int* in_sizes, int n_in,
                              void* d_out, int out_size, void* d_ws, size_t ws_size,
                              hipStream_t stream) {
    const int*   x        = (const int*)  d_in[0];
    const int*   wci      = (const int*)  d_in[1];
    const float* word_emb = (const float*)d_in[2];
    const float* char_emb = (const float*)d_in[3];
    const float* conv_w   = (const float*)d_in[4];
    const float* conv_b   = (const float*)d_in[5];
    const float* fc1_w    = (const float*)d_in[6];
    const float* fc1_b    = (const float*)d_in[7];
    const float* fc2_w    = (const float*)d_in[8];
    const float* fc2_b    = (const float*)d_in[9];
    float* out = (float*)d_out;

    char* ws = (char*)d_ws;
    short* wbf  = (short*)(ws + ((size_t)8  << 20));                  // 2 MB
    short* w2bf = (short*)(ws + ((size_t)10 << 20));                  // 0.5 MB
    _Float16* gt4 = (_Float16*)(ws + ((size_t)11 << 20));             // 50 KB

    prep_kernel<<<5195, 256, 0, stream>>>(fc1_w, fc1_b, fc2_w, char_emb,
                                          conv_w, wbf, w2bf, gt4);
    fused_kernel<<<256, 512, 0, stream>>>(x, wci, word_emb, conv_b, gt4,
                                          wbf, w2bf, fc2_b, out);
}

// Round 14
// 171.814 us; speedup vs baseline: 1.1238x; 1.1238x over previous
//
#include <hip/hip_runtime.h>
#include <hip/hip_bf16.h>

// B=16384 W=5 L=20 E=50 V=100000 C=128 H=4096 O=50
// wbf  = bf16 fc1 weights in MFMA A-frag layout:                 ws+8M    (2 MB)
// w2bf = bf16 fc2 weights in MFMA B-frag layout:                 ws+10M   (0.5 MB)
// gt4  = conv table fp16 [128][50][4] = {kk0,kk1,kk2,pad}        ws+11M   (50 KB)
// R13 post-mortem: fp16 table -3.5us only, VALUBusy 49->56%: prologue's
// binding pipe flipped to VALU (~60 cvt + ~59 f32 ops per word-channel);
// main loop tanh uses ~10-instr precise div x16/thread/chunk.
// R14: (1) conv adds+max in _Float16 (v_add_f16/v_max_f16, 1 cvt at end:
// ~62 instr/word, was ~120). Precision: fp16 add err <=2.4e-4 abs, below
// the bf16-ha rounding that dominates absmax. (2) tanh via v_rcp_f32
// (1-ulp; bf16 store keeps 8 bits) + fmaf: 5 instr vs ~15.
// Structure / LDS maps / swizzles byte-identical to R13 (passed).

typedef __attribute__((ext_vector_type(8))) short short8;
typedef __attribute__((ext_vector_type(4))) float float4v;
typedef __attribute__((ext_vector_type(4))) _Float16 half4v;

__device__ inline short bf16b(float f) {
    __hip_bfloat16 h = __float2bfloat16(f);
    return *reinterpret_cast<short*>(&h);
}
__device__ inline uint packbf2(float a, float b) {
    return (uint)(ushort)bf16b(a) | ((uint)(ushort)bf16b(b) << 16);
}
__device__ inline void gload_lds16(const void* g, void* l) {
    __builtin_amdgcn_global_load_lds(
        (const __attribute__((address_space(1))) unsigned int*)g,
        (__attribute__((address_space(3))) unsigned int*)l, 16, 0, 0);
}
__device__ inline _Float16 hmax(_Float16 a, _Float16 b) { return a > b ? a : b; }

// ---------------------------------------------------------------------------
// Merged prep: wbf (blocks 0..4095), w2bf (..5119), gt4 fp16 (..5194)
// ---------------------------------------------------------------------------
__global__ __launch_bounds__(256) void prep_kernel(
    const float* __restrict__ fc1_w, const float* __restrict__ fc1_b,
    const float* __restrict__ fc2_w, const float* __restrict__ char_emb,
    const float* __restrict__ conv_w, short* __restrict__ wbf,
    short* __restrict__ w2bf, _Float16* __restrict__ gt4)
{
    const int bid = blockIdx.x;
    if (bid < 4096) {                       // fc1 weights+bias -> frag order
        int idx = bid * 256 + threadIdx.x;  // n*256 + k
        int n = idx >> 8, k = idx & 255;
        float v = (k < 250) ? fc1_w[n * 250 + k] : (k == 250 ? fc1_b[n] : 0.f);
        int CT = n >> 4, mm = n & 15;
        int ks = k >> 5, qq = (k >> 3) & 3, j = k & 7;
        wbf[((CT * 8 + ks) * 64 + qq * 16 + mm) * 8 + j] = bf16b(v);
    } else if (bid < 5120) {                // fc2 weights (pad 64) -> frag order
        int idx = (bid - 4096) * 256 + threadIdx.x;   // o*4096 + k
        int o = idx >> 12, k = idx & 4095;
        float v = (o < 50) ? fc2_w[idx] : 0.f;
        int Ot = o >> 4, mm = o & 15;
        int kst = k >> 5, qq = (k >> 3) & 3, j = k & 7;
        w2bf[((kst * 4 + Ot) * 64 + qq * 16 + mm) * 8 + j] = bf16b(v);
    } else {                                // conv table -> fp16 [c][o][4] 8B slots
        int idx = (bid - 5120) * 256 + threadIdx.x;   // < 19200
        if (idx >= 19200) return;
        int c = idx / 150, rem = idx - c * 150;
        int kk = rem / 50, o = rem - kk * 50;
        const float* ce = char_emb + c * 50;
        const float* w  = conv_w + o * 150 + kk;
        float s = 0.f;
        #pragma unroll 10
        for (int i = 0; i < 50; ++i) s += ce[i] * w[i * 3];
        gt4[(c * 50 + o) * 4 + kk] = (_Float16)s;
        if (kk == 2) gt4[(c * 50 + o) * 4 + 3] = (_Float16)0.f;   // pad
    }
}

// ---------------------------------------------------------------------------
// Fused conv + fc1 + tanh + fc2 + softmax. 256 blocks x 512 thr, 64 rows.
// LDS map (147456 B total):
//   prologue: gt4 table [0,51200) | cpackS [51200,57600) | xsS [..58880)
//             haS (64x256 bf16, XOR-swz) [110080,142848)
//   main:     Bs dbuf [0,131072) | hsb [131072,147456)
//   epilogue: partf[4][64][64] fp32 [0,65536)
// Waves 2x4: wr = wv>>2 (row half), wc = wv&3 (col quarter = fc2 k-frag).
// Wave-private hs handoff -> one __syncthreads per chunk (R8-proven).
// ---------------------------------------------------------------------------
__global__ __launch_bounds__(512, 1) void fused_kernel(
    const int* __restrict__ x, const int* __restrict__ wci,
    const float* __restrict__ word_emb, const float* __restrict__ conv_b,
    const _Float16* __restrict__ gt4, const short* __restrict__ wbf,
    const short* __restrict__ w2bf, const float* __restrict__ fc2_b,
    float* __restrict__ out)
{
    __shared__ char smem[147456];
    short8* Bsv   = (short8*)smem;               // main loop: [2][4096] frags
    char*   hsb   = smem + 131072;               // 16 KB
    float*  partf = (float*)smem;                // epilogue alias
    char*   gsb   = smem;                        // prologue: conv table (50 KB)
    uint*   cpackS = (uint*)(smem + 51200);      // 320 x 5
    int*    xsS    = (int*)(smem + 57600);       // 320
    char*   haS    = smem + 110080;              // 64 rows x 512 B, swizzled

    const int tid  = threadIdx.x;
    const int lane = tid & 63;
    const int wv   = tid >> 6;
    const int wr = wv >> 2, wc = wv & 3;
    const int q = lane >> 4, m = lane & 15;
    const int m0 = blockIdx.x * 64;
    const int q2base = q >> 1, slot = q & 1;

    const short8* wbfv  = (const short8*)wbf;
    const short8* w2bfv = (const short8*)w2bf;

    // ================= PROLOGUE: conv for this block's 320 words ==========
    {   // stage fp16 table (51200 B) as float4
        const float4* g4 = (const float4*)gt4;
        float4* s4 = (float4*)gsb;
        #pragma unroll
        for (int i = 0; i < 7; ++i) {
            int idx = i * 512 + tid;
            if (idx < 3200) s4[idx] = g4[idx];
        }
    }
    if (tid < 320) {                             // char ids + xid
        const int xid = x[m0 * 5 + tid];
        xsS[tid] = xid;
        const int* crow = wci + (size_t)xid * 20;
        int cid[20];
        #pragma unroll
        for (int p = 0; p < 20; ++p) cid[p] = crow[p];
        #pragma unroll
        for (int u = 0; u < 5; ++u)
            cpackS[tid * 5 + u] = (uint)cid[u * 4] | ((uint)cid[u * 4 + 1] << 8)
                                | ((uint)cid[u * 4 + 2] << 16) | ((uint)cid[u * 4 + 3] << 24);
    }
    // K-bias cols 250..255 (independent of conv; hoisted off critical path)
    if (tid < 384) {
        const int s = tid / 6, j = tid - s * 6;
        const int byteoff = (s * 512 + (250 + j) * 2) ^ ((s & 7) << 4);
        *(short*)(haS + byteoff) = bf16b(j == 0 ? 1.f : 0.f);
    }
    __syncthreads();

    {   // conv: wave wv handles words (g*8+j)*8+wv; lane = out channel.
        // All adds + running max in fp16 (v_add_f16/v_max_f16): table is
        // already fp16; sums |S|<=0.5 -> add-rounding <=2.4e-4 abs, below
        // ha's bf16 rounding. One cvt to f32 at the end.
        const int oc = (lane < 50) ? lane : 49;
        const float cbias = conv_b[oc];
        const int oc8 = oc * 8;
        for (int g = 0; g < 5; ++g) {
            float werv[8];                       // 8 gathers in flight (MLP)
            #pragma unroll
            for (int j = 0; j < 8; ++j) {
                const int w = (g * 8 + j) * 8 + wv;
                werv[j] = word_emb[(size_t)xsS[w] * 50 + oc];
            }
            #pragma unroll
            for (int j = 0; j < 8; ++j) {
                const int w = (g * 8 + j) * 8 + wv;
                uint cw[5];
                #pragma unroll
                for (int u = 0; u < 5; ++u) cw[u] = cpackS[w * 5 + u];
                int cb[20];
                #pragma unroll
                for (int p = 0; p < 20; ++p) {
                    const int c = (int)((cw[p >> 2] >> ((p & 3) * 8)) & 0xFF);
                    cb[p] = c * 400 + oc8;       // byte offset of 8B slot
                }
                // phase 1: positions 0..10 (one b64 per tap)
                half4v r[11];
                #pragma unroll
                for (int l = 0; l < 11; ++l) r[l] = *(const half4v*)(gsb + cb[l]);
                _Float16 mxh = r[0].y + r[1].z;          // (y+x)+z order kept
                #pragma unroll
                for (int l = 1; l < 10; ++l) {
                    _Float16 s = r[l].y + r[l - 1].x + r[l + 1].z;
                    mxh = hmax(mxh, s);
                }
                const half4v r9 = r[9], r10 = r[10];
                // phase 2: positions 11..19
                half4v qv[9];
                #pragma unroll
                for (int l = 0; l < 9; ++l) qv[l] = *(const half4v*)(gsb + cb[11 + l]);
                mxh = hmax(mxh, (_Float16)(r10.y + r9.x + qv[0].z));     // l=10
                mxh = hmax(mxh, (_Float16)(qv[0].y + r10.x + qv[1].z));  // l=11
                #pragma unroll
                for (int l = 12; l < 19; ++l) {
                    _Float16 s = qv[l - 11].y + qv[l - 12].x + qv[l - 10].z;
                    mxh = hmax(mxh, s);
                }
                mxh = hmax(mxh, (_Float16)(qv[8].y + qv[7].x));          // l=19

                if (lane < 50) {
                    const int s = w / 5, wp = w - s * 5;
                    const int byteoff = (s * 512 + (wp * 50 + oc) * 2) ^ ((s & 7) << 4);
                    *(short*)(haS + byteoff) = bf16b((float)mxh + cbias + werv[j]);
                }
            }
        }
    }
    __syncthreads();                             // conv done; table dead

    // issue B(0) staging now (overlaps av loads; table region is dead)
    #pragma unroll
    for (int i = 0; i < 8; ++i)
        gload_lds16(wbfv + i * 512 + tid, Bsv + i * 512 + tid);

    // ---- A-frags from haS (swizzled b128 reads): 16 frags = 64 VGPR ----
    short8 av[2][8];
    #pragma unroll
    for (int mt = 0; mt < 2; ++mt)
        #pragma unroll
        for (int ks = 0; ks < 8; ++ks) {
            const int r = wr * 32 + mt * 16 + m;
            const int byteoff = (r * 512 + ks * 64 + q * 16) ^ ((r & 7) << 4);
            av[mt][ks] = *(const short8*)(haS + byteoff);
        }
    #pragma unroll
    for (int mt = 0; mt < 2; ++mt)
        #pragma unroll
        for (int ks = 0; ks < 8; ++ks)
            asm volatile("" : "+v"(av[mt][ks]));
    __syncthreads();                             // drains vmcnt: B(0) ready

    // ================= MAIN LOOP (R8 body, full K: 32 chunks) =============
    float4v acc2[2][4] = {};    // fc2 partial: [row-tile mt][out-tile], k = wc

    #pragma unroll 4
    for (int chg = 0; chg < 32; ++chg) {
        const int buf = chg & 1;

        short8 b2[4];
        #pragma unroll
        for (int Ot = 0; Ot < 4; ++Ot)
            b2[Ot] = w2bfv[(size_t)((chg * 4 + wc) * 4 + Ot) * 64 + lane];

        // async prefetch (chg=31 overruns into w2bf: in-bounds, drained,
        // then overwritten by the partf spill before any read)
        #pragma unroll
        for (int i = 0; i < 8; ++i)
            gload_lds16(wbfv + (size_t)(chg + 1) * 4096 + i * 512 + tid,
                        Bsv + (buf ^ 1) * 4096 + i * 512 + tid);

        // ---- fc1: rows [wr*32,+32) x cols [chg*128 + wc*32, +32) ----
        float4v acc[2][2] = {};
        #pragma unroll
        for (int ks = 0; ks < 8; ++ks) {
            short8 bv[2];
            #pragma unroll
            for (int nt = 0; nt < 2; ++nt)
                bv[nt] = Bsv[buf * 4096 + ((wc * 2 + nt) * 8 + ks) * 64 + lane];
            #pragma unroll
            for (int mt = 0; mt < 2; ++mt)
                #pragma unroll
                for (int nt = 0; nt < 2; ++nt)
                    acc[mt][nt] = __builtin_amdgcn_mfma_f32_16x16x32_bf16(
                        bv[nt], av[mt][ks], acc[mt][nt], 0, 0, 0);
        }

        // ---- tanh (v_rcp fast path) + pack to own hs frags ----
        #pragma unroll
        for (int mt = 0; mt < 2; ++mt) {
            const int frag = (wr * 2 + mt) * 4 + wc;
            #pragma unroll
            for (int nt = 0; nt < 2; ++nt) {
                float tv[4];
                #pragma unroll
                for (int r = 0; r < 4; ++r) {
                    float rc = __builtin_amdgcn_rcpf(
                        __expf(2.f * acc[mt][nt][r]) + 1.f);
                    tv[r] = fmaf(-2.f, rc, 1.f);
                }
                const int q2 = nt * 2 + q2base;
                const uint p0 = packbf2(tv[0], tv[1]);
                const uint p1 = packbf2(tv[2], tv[3]);
                *(uint2*)(hsb + ((frag * 64 + q2 * 16 + m) * 16 + slot * 8))
                    = make_uint2(p0, p1);
            }
        }

        // ---- fc2 partial: read back OWN frags (same-wave order, no bar) ----
        {
            short8 a2[2];
            #pragma unroll
            for (int mt = 0; mt < 2; ++mt)
                a2[mt] = *(const short8*)(hsb
                    + (((wr * 2 + mt) * 4 + wc) * 64 + lane) * 16);
            #pragma unroll
            for (int mt = 0; mt < 2; ++mt)
                #pragma unroll
                for (int Ot = 0; Ot < 4; ++Ot)
                    acc2[mt][Ot] = __builtin_amdgcn_mfma_f32_16x16x32_bf16(
                        a2[mt], b2[Ot], acc2[mt][Ot], 0, 0, 0);
        }

        __syncthreads();    // Bs[buf] reads done + prefetch vmcnt drained
    }

    // ================= EPILOGUE: reduce + bias + softmax ==================
    #pragma unroll
    for (int mt = 0; mt < 2; ++mt)
        #pragma unroll
        for (int Ot = 0; Ot < 4; ++Ot)
            #pragma unroll
            for (int r = 0; r < 4; ++r)
                partf[(size_t)wc * 4096
                      + ((wr * 2 + mt) * 16 + q * 4 + r) * 64 + Ot * 16 + m]
                    = acc2[mt][Ot][r];
    __syncthreads();

    #pragma unroll
    for (int t = 0; t < 8; ++t) {
        int idx = t * 512 + tid;           // row*64 + col
        int col = idx & 63;
        float lg = partf[idx] + partf[4096 + idx]
                 + partf[8192 + idx] + partf[12288 + idx];
        partf[idx] = (col < 50) ? lg + fc2_b[col] : -1e30f;
    }
    __syncthreads();

    #pragma unroll
    for (int rr = 0; rr < 8; ++rr) {
        const int row = wv * 8 + rr;
        float v = partf[row * 64 + lane];
        float mx = v;
        #pragma unroll
        for (int off = 32; off > 0; off >>= 1) mx = fmaxf(mx, __shfl_xor(mx, off));
        float e = __expf(v - mx);
        float s = e;
        #pragma unroll
        for (int off = 32; off > 0; off >>= 1) s += __shfl_xor(s, off);
        if (lane < 50)
            out[(size_t)(m0 + row) * 50 + lane] = e / s;
    }
}

// ---------------------------------------------------------------------------
extern "C" void kernel_launch(void* const* d_in, const int* in_sizes, int n_in,
                              void* d_out, int out_size, void* d_ws, size_t ws_size,
                              hipStream_t stream) {
    const int*   x        = (const int*)  d_in[0];
    const int*   wci      = (const int*)  d_in[1];
    const float* word_emb = (const float*)d_in[2];
    const float* char_emb = (const float*)d_in[3];
    const float* conv_w   = (const float*)d_in[4];
    const float* conv_b   = (const float*)d_in[5];
    const float* fc1_w    = (const float*)d_in[6];
    const float* fc1_b    = (const float*)d_in[7];
    const float* fc2_w    = (const float*)d_in[8];
    const float* fc2_b    = (const float*)d_in[9];
    float* out = (float*)d_out;

    char* ws = (char*)d_ws;
    short* wbf  = (short*)(ws + ((size_t)8  << 20));                  // 2 MB
    short* w2bf = (short*)(ws + ((size_t)10 << 20));                  // 0.5 MB
    _Float16* gt4 = (_Float16*)(ws + ((size_t)11 << 20));             // 50 KB

    prep_kernel<<<5195, 256, 0, stream>>>(fc1_w, fc1_b, fc2_w, char_emb,
                                          conv_w, wbf, w2bf, gt4);
    fused_kernel<<<256, 512, 0, stream>>>(x, wci, word_emb, conv_b, gt4,
                                          wbf, w2bf, fc2_b, out);
}